// Round 1
// baseline (2807.693 us; speedup 1.0000x reference)
//
#include <hip/hip_runtime.h>

// e3jLayer: per-edge equivariant tensor product + segment-sum + linear.
//   d = normalize(pos[r] - pos[s])
//   out0 = x0 + (x1 . d) * INV_S3
//   out1 = x0*d + x1 + (x1 x d) * INV_S2
//   agg[r] += tp ; out = (agg/32) @ W + b
// Baseline: atomic scatter-add into d_out, then in-place W transform.

#define F_DIM 16
#define IR_DIM 4

__global__ void __launch_bounds__(256) edge_kernel(
    const float* __restrict__ pos,
    const float* __restrict__ nf,
    const int* __restrict__ senders,
    const int* __restrict__ receivers,
    float* __restrict__ agg,
    int E)
{
    const float INV_S3 = 0.5773502691896258f; // 1/sqrt(3)
    const float INV_S2 = 0.7071067811865476f; // 1/sqrt(2)
    const float EPS = 1e-9f;

    long idx = (long)blockIdx.x * blockDim.x + threadIdx.x;
    int e = (int)(idx >> 4);
    if (e >= E) return;
    int f = (int)(idx & 15);

    int s = senders[e];
    int r = receivers[e];

    // edge direction (redundant across the 16 lanes of this edge; cache-broadcast)
    float dx = pos[3 * r + 0] - pos[3 * s + 0];
    float dy = pos[3 * r + 1] - pos[3 * s + 1];
    float dz = pos[3 * r + 2] - pos[3 * s + 2];
    float norm = sqrtf(dx * dx + dy * dy + dz * dz) + EPS;
    float inv = 1.0f / norm;
    dx *= inv; dy *= inv; dz *= inv;

    const float4 x = ((const float4*)nf)[(size_t)s * F_DIM + f];
    float x0 = x.x, x1 = x.y, x2 = x.z, x3 = x.w;

    float dot = x1 * dx + x2 * dy + x3 * dz;
    float o0 = x0 + dot * INV_S3;

    // cross(x1_vec, d)
    float c0 = x2 * dz - x3 * dy;
    float c1 = x3 * dx - x1 * dz;
    float c2 = x1 * dy - x2 * dx;

    float o1 = x0 * dx + x1 + c0 * INV_S2;
    float o2 = x0 * dy + x2 + c1 * INV_S2;
    float o3 = x0 * dz + x3 + c2 * INV_S2;

    float* dst = agg + ((size_t)r * F_DIM + f) * IR_DIM;
    atomicAdd(dst + 0, o0);
    atomicAdd(dst + 1, o1);
    atomicAdd(dst + 2, o2);
    atomicAdd(dst + 3, o3);
}

__global__ void __launch_bounds__(256) finish_kernel(
    const float* __restrict__ W,
    const float* __restrict__ b,
    float* __restrict__ out,
    int NF)
{
    int i = blockIdx.x * blockDim.x + threadIdx.x;
    if (i >= NF) return;
    float4 v = ((float4*)out)[i];
    const float inv_denom = 1.0f / 32.0f;
    float a0 = v.x * inv_denom;
    float a1 = v.y * inv_denom;
    float a2 = v.z * inv_denom;
    float a3 = v.w * inv_denom;
    float4 o;
    o.x = a0 * W[0] + a1 * W[4] + a2 * W[8]  + a3 * W[12] + b[0];
    o.y = a0 * W[1] + a1 * W[5] + a2 * W[9]  + a3 * W[13] + b[1];
    o.z = a0 * W[2] + a1 * W[6] + a2 * W[10] + a3 * W[14] + b[2];
    o.w = a0 * W[3] + a1 * W[7] + a2 * W[11] + a3 * W[15] + b[3];
    ((float4*)out)[i] = o;
}

extern "C" void kernel_launch(void* const* d_in, const int* in_sizes, int n_in,
                              void* d_out, int out_size, void* d_ws, size_t ws_size,
                              hipStream_t stream)
{
    const float* pos      = (const float*)d_in[0];
    const float* nf       = (const float*)d_in[1];
    const float* W        = (const float*)d_in[2];
    const float* b        = (const float*)d_in[3];
    const int*   senders  = (const int*)d_in[4];
    const int*   receivers= (const int*)d_in[5];

    int N = in_sizes[0] / 3;
    int E = in_sizes[4];
    float* out = (float*)d_out;

    // zero the accumulator (d_out doubles as agg buffer)
    hipMemsetAsync(out, 0, (size_t)N * F_DIM * IR_DIM * sizeof(float), stream);

    long total = (long)E * F_DIM;
    int blk = 256;
    long grid = (total + blk - 1) / blk;
    edge_kernel<<<(dim3)(unsigned)grid, blk, 0, stream>>>(pos, nf, senders, receivers, out, E);

    int NF = N * F_DIM;
    finish_kernel<<<(NF + blk - 1) / blk, blk, 0, stream>>>(W, b, out, NF);
}

// Round 2
// 637.736 us; speedup vs baseline: 4.4026x; 4.4026x over previous
//
#include <hip/hip_runtime.h>

// e3jLayer: per-edge equivariant tensor product + segment-sum + linear.
// Round 2: replace global atomic scatter (204.8M f32 atomics -> 3.28 GB HBM RMW
// traffic) with per-launch CSR build + register-accumulating gather.
//   1. hist:    deg[r]++ per edge                    (3.2M int atomics, distributed)
//   2. alloc:   start[n] = block-aggregated cursor alloc of deg[n] (no scan needed;
//               CSR region order is irrelevant)
//   3. scatter: csr_s[cur[r]++] = sender             (3.2M int atomics, distributed)
//   4. gather:  thread (n,f) accumulates over deg[n] edges in registers,
//               writes (acc/32)@W + b once. Zero f32 atomics.

#define F_DIM 16

__global__ void __launch_bounds__(256) hist_kernel(
    const int* __restrict__ receivers, int* __restrict__ deg, int E)
{
    int e = blockIdx.x * blockDim.x + threadIdx.x;
    if (e >= E) return;
    atomicAdd(&deg[receivers[e]], 1);
}

__global__ void __launch_bounds__(256) alloc_kernel(
    const int* __restrict__ deg, int* __restrict__ start, int* __restrict__ cur,
    int* __restrict__ cursor, int N)
{
    __shared__ int tmp[256];
    __shared__ int base;
    int t = threadIdx.x;
    int n = blockIdx.x * blockDim.x + t;
    int v = (n < N) ? deg[n] : 0;
    tmp[t] = v;
    __syncthreads();
    // inclusive Hillis-Steele scan over the block
    for (int off = 1; off < 256; off <<= 1) {
        int x = (t >= off) ? tmp[t - off] : 0;
        __syncthreads();
        tmp[t] += x;
        __syncthreads();
    }
    int incl = tmp[t];
    if (t == 255) base = atomicAdd(cursor, incl);  // incl == block total at t=255
    __syncthreads();
    int my_start = base + incl - v;  // exclusive scan
    if (n < N) { start[n] = my_start; cur[n] = my_start; }
}

__global__ void __launch_bounds__(256) scatter_kernel(
    const int* __restrict__ senders, const int* __restrict__ receivers,
    int* __restrict__ cur, int* __restrict__ csr_s, int E)
{
    int e = blockIdx.x * blockDim.x + threadIdx.x;
    if (e >= E) return;
    int p = atomicAdd(&cur[receivers[e]], 1);
    csr_s[p] = senders[e];
}

__global__ void __launch_bounds__(256) gather_kernel(
    const float* __restrict__ pos,
    const float* __restrict__ nf,
    const int* __restrict__ csr_s,
    const int* __restrict__ start,
    const int* __restrict__ deg,
    const float* __restrict__ W,
    const float* __restrict__ b,
    float* __restrict__ out,
    int N)
{
    const float INV_S3 = 0.5773502691896258f; // 1/sqrt(3)
    const float INV_S2 = 0.7071067811865476f; // 1/sqrt(2)
    const float EPS = 1e-9f;

    int tid = blockIdx.x * blockDim.x + threadIdx.x;
    int n = tid >> 4;
    if (n >= N) return;
    int f = tid & 15;

    // receiver position (broadcast across the 16 f-lanes of this node)
    float rx = pos[3 * n + 0];
    float ry = pos[3 * n + 1];
    float rz = pos[3 * n + 2];

    int s0 = start[n];
    int dcnt = deg[n];

    float a0 = 0.f, a1 = 0.f, a2 = 0.f, a3 = 0.f;

    const float4* nf4 = (const float4*)nf;

    int s = (dcnt > 0) ? csr_s[s0] : 0;
    for (int j = 0; j < dcnt; ++j) {
        int s_next = (j + 1 < dcnt) ? csr_s[s0 + j + 1] : 0;  // prefetch

        float dx = rx - pos[3 * s + 0];
        float dy = ry - pos[3 * s + 1];
        float dz = rz - pos[3 * s + 2];
        float inv = 1.0f / (sqrtf(dx * dx + dy * dy + dz * dz) + EPS);
        dx *= inv; dy *= inv; dz *= inv;

        float4 x = nf4[(size_t)s * F_DIM + f];  // coalesced 256B per edge-row
        float x0 = x.x, x1 = x.y, x2 = x.z, x3 = x.w;

        float dot = x1 * dx + x2 * dy + x3 * dz;
        a0 += x0 + dot * INV_S3;

        float c0 = x2 * dz - x3 * dy;
        float c1 = x3 * dx - x1 * dz;
        float c2 = x1 * dy - x2 * dx;

        a1 += x0 * dx + x1 + c0 * INV_S2;
        a2 += x0 * dy + x2 + c1 * INV_S2;
        a3 += x0 * dz + x3 + c2 * INV_S2;

        s = s_next;
    }

    const float sc = 1.0f / 32.0f;
    a0 *= sc; a1 *= sc; a2 *= sc; a3 *= sc;

    float4 o;
    o.x = a0 * W[0] + a1 * W[4] + a2 * W[8]  + a3 * W[12] + b[0];
    o.y = a0 * W[1] + a1 * W[5] + a2 * W[9]  + a3 * W[13] + b[1];
    o.z = a0 * W[2] + a1 * W[6] + a2 * W[10] + a3 * W[14] + b[2];
    o.w = a0 * W[3] + a1 * W[7] + a2 * W[11] + a3 * W[15] + b[3];
    ((float4*)out)[tid] = o;
}

extern "C" void kernel_launch(void* const* d_in, const int* in_sizes, int n_in,
                              void* d_out, int out_size, void* d_ws, size_t ws_size,
                              hipStream_t stream)
{
    const float* pos       = (const float*)d_in[0];
    const float* nf        = (const float*)d_in[1];
    const float* W         = (const float*)d_in[2];
    const float* b         = (const float*)d_in[3];
    const int*   senders   = (const int*)d_in[4];
    const int*   receivers = (const int*)d_in[5];

    int N = in_sizes[0] / 3;
    int E = in_sizes[4];
    float* out = (float*)d_out;

    // ws layout: [cursor(1)][deg(N)][start(N)][cur(N)][csr_s(E)]  (ints)
    int* cursor = (int*)d_ws;
    int* deg    = cursor + 1;
    int* start  = deg + N;
    int* cur    = start + N;
    int* csr_s  = cur + N;

    // zero cursor + deg (contiguous)
    hipMemsetAsync(cursor, 0, (size_t)(1 + N) * sizeof(int), stream);

    int blk = 256;
    hist_kernel<<<(E + blk - 1) / blk, blk, 0, stream>>>(receivers, deg, E);
    alloc_kernel<<<(N + blk - 1) / blk, blk, 0, stream>>>(deg, start, cur, cursor, N);
    scatter_kernel<<<(E + blk - 1) / blk, blk, 0, stream>>>(senders, receivers, cur, csr_s, E);

    long total = (long)N * F_DIM;
    gather_kernel<<<(unsigned)((total + blk - 1) / blk), blk, 0, stream>>>(
        pos, nf, csr_s, start, deg, W, b, out, N);
}

// Round 3
// 437.555 us; speedup vs baseline: 6.4168x; 1.4575x over previous
//
#include <hip/hip_runtime.h>

// e3jLayer: per-edge equivariant tensor product + segment-sum + linear.
// Round 3: atomic-free scatter. The histogram's atomicAdd return value IS the
// edge's rank within its receiver, so the CSR permutation needs no cur[] atomics:
//   1. hist:    rank[e] = atomicAdd(&deg[r], 1)      (the only per-edge atomics)
//   2. alloc:   start[n] = exclusive-scan alloc of deg[n] (order irrelevant)
//   3. scatter: csr_s[start[r] + rank[e]] = sender   (pure permutation, no atomics)
//   4. gather:  thread (n,f) register-accumulates deg[n] edges, writes
//               (acc/32)@W + b once.

#define F_DIM 16

__global__ void __launch_bounds__(256) hist_kernel(
    const int* __restrict__ receivers, int* __restrict__ deg,
    int* __restrict__ rank, int E)
{
    int e = blockIdx.x * blockDim.x + threadIdx.x;
    if (e >= E) return;
    rank[e] = atomicAdd(&deg[receivers[e]], 1);
}

__global__ void __launch_bounds__(256) alloc_kernel(
    const int* __restrict__ deg, int* __restrict__ start,
    int* __restrict__ cursor, int N)
{
    __shared__ int tmp[256];
    __shared__ int base;
    int t = threadIdx.x;
    int n = blockIdx.x * blockDim.x + t;
    int v = (n < N) ? deg[n] : 0;
    tmp[t] = v;
    __syncthreads();
    // inclusive Hillis-Steele scan over the block
    for (int off = 1; off < 256; off <<= 1) {
        int x = (t >= off) ? tmp[t - off] : 0;
        __syncthreads();
        tmp[t] += x;
        __syncthreads();
    }
    int incl = tmp[t];
    if (t == 255) base = atomicAdd(cursor, incl);  // incl == block total at t=255
    __syncthreads();
    if (n < N) start[n] = base + incl - v;  // exclusive scan
}

__global__ void __launch_bounds__(256) scatter_kernel(
    const int* __restrict__ senders, const int* __restrict__ receivers,
    const int* __restrict__ rank, const int* __restrict__ start,
    int* __restrict__ csr_s, int E)
{
    int e = blockIdx.x * blockDim.x + threadIdx.x;
    if (e >= E) return;
    csr_s[start[receivers[e]] + rank[e]] = senders[e];
}

__global__ void __launch_bounds__(256) gather_kernel(
    const float* __restrict__ pos,
    const float* __restrict__ nf,
    const int* __restrict__ csr_s,
    const int* __restrict__ start,
    const int* __restrict__ deg,
    const float* __restrict__ W,
    const float* __restrict__ b,
    float* __restrict__ out,
    int N)
{
    const float INV_S3 = 0.5773502691896258f; // 1/sqrt(3)
    const float INV_S2 = 0.7071067811865476f; // 1/sqrt(2)
    const float EPS = 1e-9f;

    int tid = blockIdx.x * blockDim.x + threadIdx.x;
    int n = tid >> 4;
    if (n >= N) return;
    int f = tid & 15;

    // receiver position (broadcast across the 16 f-lanes of this node)
    float rx = pos[3 * n + 0];
    float ry = pos[3 * n + 1];
    float rz = pos[3 * n + 2];

    int s0 = start[n];
    int dcnt = deg[n];

    float a0 = 0.f, a1 = 0.f, a2 = 0.f, a3 = 0.f;

    const float4* nf4 = (const float4*)nf;

    int s = (dcnt > 0) ? csr_s[s0] : 0;
    for (int j = 0; j < dcnt; ++j) {
        int s_next = (j + 1 < dcnt) ? csr_s[s0 + j + 1] : 0;  // prefetch

        float dx = rx - pos[3 * s + 0];
        float dy = ry - pos[3 * s + 1];
        float dz = rz - pos[3 * s + 2];
        float inv = 1.0f / (sqrtf(dx * dx + dy * dy + dz * dz) + EPS);
        dx *= inv; dy *= inv; dz *= inv;

        float4 x = nf4[(size_t)s * F_DIM + f];  // coalesced 256B per edge-row
        float x0 = x.x, x1 = x.y, x2 = x.z, x3 = x.w;

        float dot = x1 * dx + x2 * dy + x3 * dz;
        a0 += x0 + dot * INV_S3;

        float c0 = x2 * dz - x3 * dy;
        float c1 = x3 * dx - x1 * dz;
        float c2 = x1 * dy - x2 * dx;

        a1 += x0 * dx + x1 + c0 * INV_S2;
        a2 += x0 * dy + x2 + c1 * INV_S2;
        a3 += x0 * dz + x3 + c2 * INV_S2;

        s = s_next;
    }

    const float sc = 1.0f / 32.0f;
    a0 *= sc; a1 *= sc; a2 *= sc; a3 *= sc;

    float4 o;
    o.x = a0 * W[0] + a1 * W[4] + a2 * W[8]  + a3 * W[12] + b[0];
    o.y = a0 * W[1] + a1 * W[5] + a2 * W[9]  + a3 * W[13] + b[1];
    o.z = a0 * W[2] + a1 * W[6] + a2 * W[10] + a3 * W[14] + b[2];
    o.w = a0 * W[3] + a1 * W[7] + a2 * W[11] + a3 * W[15] + b[3];
    ((float4*)out)[tid] = o;
}

extern "C" void kernel_launch(void* const* d_in, const int* in_sizes, int n_in,
                              void* d_out, int out_size, void* d_ws, size_t ws_size,
                              hipStream_t stream)
{
    const float* pos       = (const float*)d_in[0];
    const float* nf        = (const float*)d_in[1];
    const float* W         = (const float*)d_in[2];
    const float* b         = (const float*)d_in[3];
    const int*   senders   = (const int*)d_in[4];
    const int*   receivers = (const int*)d_in[5];

    int N = in_sizes[0] / 3;
    int E = in_sizes[4];
    float* out = (float*)d_out;

    // ws layout: [cursor(1)][deg(N)][start(N)][rank(E)][csr_s(E)]  (ints)
    int* cursor = (int*)d_ws;
    int* deg    = cursor + 1;
    int* start  = deg + N;
    int* rank   = start + N;
    int* csr_s  = rank + E;

    // zero cursor + deg (contiguous)
    hipMemsetAsync(cursor, 0, (size_t)(1 + N) * sizeof(int), stream);

    int blk = 256;
    hist_kernel<<<(E + blk - 1) / blk, blk, 0, stream>>>(receivers, deg, rank, E);
    alloc_kernel<<<(N + blk - 1) / blk, blk, 0, stream>>>(deg, start, cursor, N);
    scatter_kernel<<<(E + blk - 1) / blk, blk, 0, stream>>>(senders, receivers, rank, start, csr_s, E);

    long total = (long)N * F_DIM;
    gather_kernel<<<(unsigned)((total + blk - 1) / blk), blk, 0, stream>>>(
        pos, nf, csr_s, start, deg, W, b, out, N);
}